// Round 5
// baseline (693.230 us; speedup 1.0000x reference)
//
#include <hip/hip_runtime.h>

#define SCALE 0.17677669529663687f   // 1/sqrt(32)
#define GAIN  0.0625f                // 1/sqrt(256)
#define LOG2E 1.4426950408889634f
#define C1    (0.17677669529663687f * 1.4426950408889634f)   // SCALE*log2e

typedef float f32x4 __attribute__((ext_vector_type(4)));
typedef short s16x8 __attribute__((ext_vector_type(8)));
typedef short s16x4 __attribute__((ext_vector_type(4)));

static __device__ __forceinline__ unsigned bfb(float f) {
  union { float f; unsigned u; } v; v.f = f;
  unsigned u = v.u;
  u += 0x7fffu + ((u >> 16) & 1u);   // RNE
  return u >> 16;
}
static __device__ __forceinline__ short f2bf(float f) { return (short)bfb(f); }

static __device__ __forceinline__ void pack4(float a, float b, float c, float d,
                                             int& lo, int& hi) {
  lo = (int)(bfb(a) | (bfb(b) << 16));
  hi = (int)(bfb(c) | (bfb(d) << 16));
}
static __device__ __forceinline__ s16x4 pks4(const f32x4& v) {
  s16x4 p;
#pragma unroll
  for (int r = 0; r < 4; ++r) p[r] = f2bf(v[r]);
  return p;
}

// Quad-swap repack: source lane (c,gs) holds q0 = X[4gs..4gs+3] (X-low half 0..15,
// 2 dwords of 4 bf16) and q1 = X[16+4gs..16+4gs+3]. Result: lane (c,g) gets
// bf16x8 = X[8g..8g+7] (same c). 8 bpermute + 4 select.
static __device__ __forceinline__ s16x8 repack8(int q0a, int q0b, int q1a, int q1b,
                                                int lane) {
  const int c = lane & 15, g = lane >> 4;
  const int s0 = ((g & 1) << 5) + c;   // 32*(g&1)+c
  const int s1 = s0 + 16;
  int a0 = __shfl(q0a, s0, 64), a1 = __shfl(q0b, s0, 64);
  int b0 = __shfl(q1a, s0, 64), b1 = __shfl(q1b, s0, 64);
  int c0 = __shfl(q0a, s1, 64), c1 = __shfl(q0b, s1, 64);
  int d0 = __shfl(q1a, s1, 64), d1 = __shfl(q1b, s1, 64);
  const bool hiH = (g >= 2);
  union { int i[4]; s16x8 v; } u;
  u.i[0] = hiH ? b0 : a0;
  u.i[1] = hiH ? b1 : a1;
  u.i[2] = hiH ? d0 : c0;
  u.i[3] = hiH ? d1 : c1;
  return u.v;
}

__global__ void prep_weights(const float* __restrict__ qw, const float* __restrict__ kw,
                             const float* __restrict__ vw, const float* __restrict__ pw,
                             short* __restrict__ wsb) {
  int i = blockIdx.x * 256 + threadIdx.x;   // 0..65535
  wsb[i]          = f2bf(qw[i] * GAIN);
  wsb[i + 65536]  = f2bf(kw[i] * GAIN);
  wsb[i + 131072] = f2bf(vw[i] * GAIN);
  wsb[i + 196608] = f2bf(pw[i] * GAIN);
}

// ---- LDS layout (bytes) ----
// XN: bf16 [64 tok][264] = 33792 (AN aliases it after projections)
// ML: f32 [64][68] = 17408 (mask * log2e)
// SN: f32 [64] = 256
#define OFF_XN 0
#define OFF_M  33792
#define OFF_SN 51200
#define LDS_TOTAL 51456

template<bool BF16W>
__global__ __launch_bounds__(512, 4)
void wattn(const float* __restrict__ x, const float* __restrict__ mask,
           const float* __restrict__ qw, const float* __restrict__ qb,
           const float* __restrict__ kw, const float* __restrict__ kb,
           const float* __restrict__ vw, const float* __restrict__ vb,
           const float* __restrict__ pw, const float* __restrict__ pb,
           const short* __restrict__ wsb, float* __restrict__ out)
{
  __shared__ __align__(16) char smem[LDS_TOTAL];
  const int tid  = threadIdx.x;
  const int lane = tid & 63;
  const int w    = tid >> 6;     // wave 0..7 = head
  const int c    = lane & 15;
  const int g    = lane >> 4;    // 0..3
  const int b    = blockIdx.x;

  const float* xg = x + (size_t)b * 16384;

  short* XN = (short*)(smem + OFF_XN);
  float* ML = (float*)(smem + OFF_M);
  float* SN = (float*)(smem + OFF_SN);
  short* AN = XN;                          // alias after projections

  const short* wq_bf = wsb;
  const short* wk_bf = wsb + 65536;
  const short* wv_bf = wsb + 131072;
  const short* wp_bf = wsb + 196608;

  auto wfragG = [&](const short* wb, const float* wf, int row, int k0) -> s16x8 {
    s16x8 r;
    if constexpr (BF16W) {
      r = *(const s16x8*)(wb + row * 256 + k0);
    } else {
      const f32x4* p = (const f32x4*)(wf + row * 256 + k0);
      f32x4 a = p[0], b2 = p[1];
#pragma unroll
      for (int j = 0; j < 4; ++j) { r[j] = f2bf(a[j] * GAIN); r[j+4] = f2bf(b2[j] * GAIN); }
    }
    return r;
  };

  // ---- P0: coalesced x load, row norms via wave reduce, XN write; mask copy ----
  {
    f32x4 xv[8];
    float ssu[8];
#pragma unroll
    for (int u = 0; u < 8; ++u) {
      xv[u] = *(const f32x4*)(xg + (u * 512 + tid) * 4);
      ssu[u] = xv[u][0]*xv[u][0] + xv[u][1]*xv[u][1] + xv[u][2]*xv[u][2] + xv[u][3]*xv[u][3];
    }
#pragma unroll
    for (int u = 0; u < 8; ++u)
#pragma unroll
      for (int d = 1; d < 64; d <<= 1) ssu[u] += __shfl_xor(ssu[u], d, 64);
#pragma unroll
    for (int u = 0; u < 8; ++u) {
      const int row = 8 * u + w;
      float s = fmaxf(sqrtf(ssu[u]), 1e-12f);
      float inv = 1.0f / s;
      if (lane == 0) SN[row] = s;
      s16x4 pk;
#pragma unroll
      for (int e = 0; e < 4; ++e) pk[e] = f2bf(xv[u][e] * inv);
      *(s16x4*)(XN + row * 264 + lane * 4) = pk;
    }
    // mask: thread t copies 8 consecutive floats (coalesced), scaled by log2e
    const f32x4* msrc = (const f32x4*)(mask + (size_t)b * 4096 + tid * 8);
    f32x4* mdst = (f32x4*)(ML + (tid >> 3) * 68 + (tid & 7) * 8);
    mdst[0] = msrc[0] * LOG2E;
    mdst[1] = msrc[1] * LOG2E;
  }
  __syncthreads();

  const int h = w;   // head
  s16x8 QB[4], KA[4], VA[2][2];

  // ---- Q projection -> QB (B-operand frags: lane c = q-token, 8 consec d) ----
  {
    f32x4 acc[2][4] = {};
#pragma unroll
    for (int kk = 0; kk < 8; ++kk) {
      const int k0 = kk * 32 + 8 * g;
      s16x8 xf[4];
#pragma unroll
      for (int ni = 0; ni < 4; ++ni) xf[ni] = *(const s16x8*)(XN + (16*ni + c) * 264 + k0);
#pragma unroll
      for (int mi = 0; mi < 2; ++mi) {
        s16x8 af = wfragG(wq_bf, qw, h*32 + 16*mi + c, k0);
#pragma unroll
        for (int ni = 0; ni < 4; ++ni)
          acc[mi][ni] = __builtin_amdgcn_mfma_f32_16x16x32_bf16(af, xf[ni], acc[mi][ni], 0, 0, 0);
      }
    }
    float b0[4], b1[4];
#pragma unroll
    for (int r = 0; r < 4; ++r) { b0[r] = qb[h*32 + 4*g + r]; b1[r] = qb[h*32 + 16 + 4*g + r]; }
#pragma unroll
    for (int ni = 0; ni < 4; ++ni) {
      int a0, a1, c0, c1;
      pack4(acc[0][ni][0]+b0[0], acc[0][ni][1]+b0[1], acc[0][ni][2]+b0[2], acc[0][ni][3]+b0[3], a0, a1);
      pack4(acc[1][ni][0]+b1[0], acc[1][ni][1]+b1[1], acc[1][ni][2]+b1[2], acc[1][ni][3]+b1[3], c0, c1);
      QB[ni] = repack8(a0, a1, c0, c1, lane);
    }
  }
  // ---- K projection -> KA (A-operand frags: lane c = key, 8 consec d) ----
  {
    f32x4 acc[2][4] = {};
#pragma unroll
    for (int kk = 0; kk < 8; ++kk) {
      const int k0 = kk * 32 + 8 * g;
      s16x8 xf[4];
#pragma unroll
      for (int ni = 0; ni < 4; ++ni) xf[ni] = *(const s16x8*)(XN + (16*ni + c) * 264 + k0);
#pragma unroll
      for (int mi = 0; mi < 2; ++mi) {
        s16x8 af = wfragG(wk_bf, kw, h*32 + 16*mi + c, k0);
#pragma unroll
        for (int ni = 0; ni < 4; ++ni)
          acc[mi][ni] = __builtin_amdgcn_mfma_f32_16x16x32_bf16(af, xf[ni], acc[mi][ni], 0, 0, 0);
      }
    }
    float b0[4], b1[4];
#pragma unroll
    for (int r = 0; r < 4; ++r) { b0[r] = kb[h*32 + 4*g + r]; b1[r] = kb[h*32 + 16 + 4*g + r]; }
#pragma unroll
    for (int ni = 0; ni < 4; ++ni) {
      int a0, a1, c0, c1;
      pack4(acc[0][ni][0]+b0[0], acc[0][ni][1]+b0[1], acc[0][ni][2]+b0[2], acc[0][ni][3]+b0[3], a0, a1);
      pack4(acc[1][ni][0]+b1[0], acc[1][ni][1]+b1[1], acc[1][ni][2]+b1[2], acc[1][ni][3]+b1[3], c0, c1);
      KA[ni] = repack8(a0, a1, c0, c1, lane);
    }
  }
  // ---- V projection (from XN, un-normalized via SN) -> VA[d-tile][key-kk] ----
  {
    f32x4 acc[4][2] = {};   // [token-tile][d-tile]
#pragma unroll
    for (int kk = 0; kk < 8; ++kk) {
      const int k0 = kk * 32 + 8 * g;
      s16x8 xf[4];
#pragma unroll
      for (int mi = 0; mi < 4; ++mi) xf[mi] = *(const s16x8*)(XN + (16*mi + c) * 264 + k0);
#pragma unroll
      for (int ni = 0; ni < 2; ++ni) {
        s16x8 bf = wfragG(wv_bf, vw, h*32 + 16*ni + c, k0);
#pragma unroll
        for (int mi = 0; mi < 4; ++mi)
          acc[mi][ni] = __builtin_amdgcn_mfma_f32_16x16x32_bf16(xf[mi], bf, acc[mi][ni], 0, 0, 0);
      }
    }
    float vbv[2];
#pragma unroll
    for (int ni = 0; ni < 2; ++ni) vbv[ni] = vb[h*32 + 16*ni + c];
#pragma unroll
    for (int ni = 0; ni < 2; ++ni)
#pragma unroll
      for (int k2 = 0; k2 < 2; ++k2) {
        f32x4 s0 = *(const f32x4*)(SN + 32*k2 + 4*g);
        f32x4 s1 = *(const f32x4*)(SN + 32*k2 + 16 + 4*g);
        int a0, a1, c0, c1;
        pack4(acc[2*k2][ni][0]*s0[0]+vbv[ni], acc[2*k2][ni][1]*s0[1]+vbv[ni],
              acc[2*k2][ni][2]*s0[2]+vbv[ni], acc[2*k2][ni][3]*s0[3]+vbv[ni], a0, a1);
        pack4(acc[2*k2+1][ni][0]*s1[0]+vbv[ni], acc[2*k2+1][ni][1]*s1[1]+vbv[ni],
              acc[2*k2+1][ni][2]*s1[2]+vbv[ni], acc[2*k2+1][ni][3]*s1[3]+vbv[ni], c0, c1);
        VA[ni][k2] = repack8(a0, a1, c0, c1, lane);
      }
  }
  __syncthreads();   // all XN reads done -> AN (aliasing XN) may be written

  // ---- attention, per q-half (2 q-tiles each): S^T -> softmax -> PB -> PV -> AN ----
#pragma unroll
  for (int hi = 0; hi < 2; ++hi) {
    f32x4 sacc[4][2];
    const f32x4 zf = {0.f, 0.f, 0.f, 0.f};
#pragma unroll
    for (int kt = 0; kt < 4; ++kt)
#pragma unroll
      for (int n2 = 0; n2 < 2; ++n2)
        sacc[kt][n2] = __builtin_amdgcn_mfma_f32_16x16x32_bf16(KA[kt], QB[2*hi + n2], zf, 0, 0, 0);
    float rs[2];
#pragma unroll
    for (int n2 = 0; n2 < 2; ++n2) {
      const int q = 16 * (2*hi + n2) + c;
      float sm = 0.f;
#pragma unroll
      for (int kt = 0; kt < 4; ++kt) {
        f32x4 mlv = *(const f32x4*)(ML + q * 68 + 16*kt + 4*g);
#pragma unroll
        for (int r = 0; r < 4; ++r) {
          float e = exp2f(sacc[kt][n2][r] * C1 + mlv[r]);
          sacc[kt][n2][r] = e;
          sm += e;
        }
      }
      sm += __shfl_xor(sm, 16, 64);
      sm += __shfl_xor(sm, 32, 64);
      rs[n2] = 1.0f / sm;
    }
#pragma unroll
    for (int n2 = 0; n2 < 2; ++n2) {
      s16x8 PBf[2];
#pragma unroll
      for (int k2 = 0; k2 < 2; ++k2) {
        int a0, a1, c0, c1;
        pack4(sacc[2*k2][n2][0]*rs[n2], sacc[2*k2][n2][1]*rs[n2],
              sacc[2*k2][n2][2]*rs[n2], sacc[2*k2][n2][3]*rs[n2], a0, a1);
        pack4(sacc[2*k2+1][n2][0]*rs[n2], sacc[2*k2+1][n2][1]*rs[n2],
              sacc[2*k2+1][n2][2]*rs[n2], sacc[2*k2+1][n2][3]*rs[n2], c0, c1);
        PBf[k2] = repack8(a0, a1, c0, c1, lane);
      }
      f32x4 pacc[2] = {};
#pragma unroll
      for (int k2 = 0; k2 < 2; ++k2)
#pragma unroll
        for (int md = 0; md < 2; ++md)
          pacc[md] = __builtin_amdgcn_mfma_f32_16x16x32_bf16(VA[md][k2], PBf[k2], pacc[md], 0, 0, 0);
      const int q = 16 * (2*hi + n2) + c;
#pragma unroll
      for (int md = 0; md < 2; ++md)
        *(s16x4*)(AN + q * 264 + h*32 + 16*md + 4*g) = pks4(pacc[md]);
    }
  }
  __syncthreads();

  // ---- P4: final projection, wave w -> out cols 32w..32w+31 ----
  {
    f32x4 facc[4][2] = {};
#pragma unroll
    for (int kk = 0; kk < 8; ++kk) {
      const int k0 = kk * 32 + 8 * g;
      s16x8 afr[4];
#pragma unroll
      for (int mi = 0; mi < 4; ++mi) afr[mi] = *(const s16x8*)(AN + (16*mi + c) * 264 + k0);
#pragma unroll
      for (int ni = 0; ni < 2; ++ni) {
        s16x8 bfr = wfragG(wp_bf, pw, 32*w + 16*ni + c, k0);
#pragma unroll
        for (int mi = 0; mi < 4; ++mi)
          facc[mi][ni] = __builtin_amdgcn_mfma_f32_16x16x32_bf16(afr[mi], bfr, facc[mi][ni], 0, 0, 0);
      }
    }
    float bpv[2];
#pragma unroll
    for (int ni = 0; ni < 2; ++ni) bpv[ni] = pb[32*w + 16*ni + c];
    float* og = out + (size_t)b * 16384;
#pragma unroll
    for (int mi = 0; mi < 4; ++mi)
#pragma unroll
      for (int ni = 0; ni < 2; ++ni)
#pragma unroll
        for (int r = 0; r < 4; ++r)
          og[(16*mi + 4*g + r) * 256 + 32*w + 16*ni + c] = facc[mi][ni][r] + bpv[ni];
  }
}

extern "C" void kernel_launch(void* const* d_in, const int* in_sizes, int n_in,
                              void* d_out, int out_size, void* d_ws, size_t ws_size,
                              hipStream_t stream) {
  const float* x    = (const float*)d_in[0];
  const float* mask = (const float*)d_in[1];
  const float* qw   = (const float*)d_in[2];
  const float* qb   = (const float*)d_in[3];
  const float* kw   = (const float*)d_in[4];
  const float* kb   = (const float*)d_in[5];
  const float* vw   = (const float*)d_in[6];
  const float* vb   = (const float*)d_in[7];
  const float* pw   = (const float*)d_in[8];
  const float* pb   = (const float*)d_in[9];
  float* out = (float*)d_out;

  if (ws_size >= 4u * 65536u * sizeof(short)) {
    short* wsb = (short*)d_ws;
    prep_weights<<<256, 256, 0, stream>>>(qw, kw, vw, pw, wsb);
    wattn<true><<<4096, 512, 0, stream>>>(x, mask, qw, qb, kw, kb, vw, vb, pw, pb, wsb, out);
  } else {
    wattn<false><<<4096, 512, 0, stream>>>(x, mask, qw, qb, kw, kb, vw, vb, pw, pb, nullptr, out);
  }
}

// Round 7
// 342.477 us; speedup vs baseline: 2.0242x; 2.0242x over previous
//
#include <hip/hip_runtime.h>

#define GAIN  0.0625f                // 1/sqrt(256)
#define LOG2E 1.4426950408889634f
#define C1    (0.17677669529663687f * 1.4426950408889634f)   // (1/sqrt(32))*log2e

typedef float f32x4 __attribute__((ext_vector_type(4)));
typedef short s16x8 __attribute__((ext_vector_type(8)));
typedef short s16x4 __attribute__((ext_vector_type(4)));
typedef _Float16 h16x4 __attribute__((ext_vector_type(4)));

union U8 { s16x4 h[2]; s16x8 v; };

static __device__ __forceinline__ short f2bf(float f) {
  union { float f; unsigned u; } v; v.f = f;
  unsigned u = v.u;
  u += 0x7fffu + ((u >> 16) & 1u);   // RNE
  return (short)(u >> 16);
}
static __device__ __forceinline__ s16x4 pks4(const f32x4& v) {
  s16x4 p;
#pragma unroll
  for (int r = 0; r < 4; ++r) p[r] = f2bf(v[r]);
  return p;
}

__global__ void prep_weights(const float* __restrict__ qw, const float* __restrict__ kw,
                             const float* __restrict__ vw, const float* __restrict__ pw,
                             short* __restrict__ wsb) {
  int i = blockIdx.x * 256 + threadIdx.x;   // 0..65535
  wsb[i]          = f2bf(qw[i] * GAIN);
  wsb[i + 65536]  = f2bf(kw[i] * GAIN);
  wsb[i + 131072] = f2bf(vw[i] * GAIN);
  wsb[i + 196608] = f2bf(pw[i] * GAIN);
}

// ---- LDS layout (bytes) ----
// XN: bf16 [64 tok][264] = 33792 (AN aliases it after projections)
// MH: f16  [64][68] = 8704  (mask * log2e)
// SC: per-wave scratch 4864 B x 8 waves = 38912
//     (Q/K bounce: [64 tok][36] stride 72B, b64 access; V/P bounce: [32][76] stride 152B)
// SN: f32 [64] = 256
// total 81664 -> rounds to 81920 = exactly 2 blocks/CU
#define OFF_XN 0
#define OFF_MH 33792
#define OFF_SC 42496
#define OFF_SN 81408
#define LDS_TOTAL 81664

template<bool BF16W>
__global__ __launch_bounds__(512, 4)
void wattn(const float* __restrict__ x, const float* __restrict__ mask,
           const float* __restrict__ qw, const float* __restrict__ qb,
           const float* __restrict__ kw, const float* __restrict__ kb,
           const float* __restrict__ vw, const float* __restrict__ vb,
           const float* __restrict__ pw, const float* __restrict__ pb,
           const short* __restrict__ wsb, float* __restrict__ out)
{
  __shared__ __align__(16) char smem[LDS_TOTAL];
  const int tid  = threadIdx.x;
  const int lane = tid & 63;
  const int w    = tid >> 6;     // wave 0..7 = head
  const int c    = lane & 15;
  const int g    = lane >> 4;    // 0..3
  const int b    = blockIdx.x;

  const float* xg = x + (size_t)b * 16384;

  short*     XN = (short*)(smem + OFF_XN);
  _Float16*  MH = (_Float16*)(smem + OFF_MH);
  float*     SN = (float*)(smem + OFF_SN);
  short*     SC = (short*)(smem + OFF_SC) + w * 2432;   // 4864 B per wave
  short*     AN = XN;                                   // alias after projections

  const short* wq_bf = wsb;
  const short* wk_bf = wsb + 65536;
  const short* wv_bf = wsb + 131072;
  const short* wp_bf = wsb + 196608;

  auto wfragG = [&](const short* wb, const float* wf, int row, int k0) -> s16x8 {
    s16x8 r;
    if constexpr (BF16W) {
      r = *(const s16x8*)(wb + row * 256 + k0);
    } else {
      const f32x4* p = (const f32x4*)(wf + row * 256 + k0);
      f32x4 a = p[0], b2 = p[1];
#pragma unroll
      for (int j = 0; j < 4; ++j) { r[j] = f2bf(a[j] * GAIN); r[j+4] = f2bf(b2[j] * GAIN); }
    }
    return r;
  };

  // ---- P0: coalesced x load, row norms via wave reduce, XN write; mask -> f16 ----
  {
    f32x4 xv[8];
    float ssu[8];
#pragma unroll
    for (int u = 0; u < 8; ++u) {
      xv[u] = *(const f32x4*)(xg + (u * 512 + tid) * 4);
      ssu[u] = xv[u][0]*xv[u][0] + xv[u][1]*xv[u][1] + xv[u][2]*xv[u][2] + xv[u][3]*xv[u][3];
    }
#pragma unroll
    for (int u = 0; u < 8; ++u)
#pragma unroll
      for (int d = 1; d < 64; d <<= 1) ssu[u] += __shfl_xor(ssu[u], d, 64);
#pragma unroll
    for (int u = 0; u < 8; ++u) {
      const int row = 8 * u + w;
      float s = fmaxf(sqrtf(ssu[u]), 1e-12f);
      float inv = 1.0f / s;
      if (lane == 0) SN[row] = s;
      s16x4 pk;
#pragma unroll
      for (int e = 0; e < 4; ++e) pk[e] = f2bf(xv[u][e] * inv);
      *(s16x4*)(XN + row * 264 + lane * 4) = pk;
    }
    // mask: thread t -> 8 consecutive floats (coalesced), scale by log2e, store f16
    const f32x4* msrc = (const f32x4*)(mask + (size_t)b * 4096 + tid * 8);
    const int mrow = tid >> 3, mcol = (tid & 7) * 8;
    f32x4 m0 = msrc[0], m1 = msrc[1];
    h16x4 h0, h1;
#pragma unroll
    for (int e = 0; e < 4; ++e) { h0[e] = (_Float16)(m0[e] * LOG2E); h1[e] = (_Float16)(m1[e] * LOG2E); }
    *(h16x4*)(MH + mrow * 68 + mcol)     = h0;
    *(h16x4*)(MH + mrow * 68 + mcol + 4) = h1;
  }
  __syncthreads();

  const int hd0 = 32 * w;   // this wave's head channel base
  s16x8 QB[4], KA[4], VA[2][2];

  // ---- Q/K projection + wave-local LDS bounce -> operand-layout frags ----
  auto projQK = [&](const short* wb, const float* wf, const float* bias, s16x8* F) {
    f32x4 acc[2][4] = {};
#pragma unroll
    for (int kk = 0; kk < 8; ++kk) {
      const int k0 = kk * 32 + 8 * g;
      s16x8 xf[4];
#pragma unroll
      for (int ni = 0; ni < 4; ++ni) xf[ni] = *(const s16x8*)(XN + (16*ni + c) * 264 + k0);
#pragma unroll
      for (int mi = 0; mi < 2; ++mi) {
        s16x8 af = wfragG(wb, wf, hd0 + 16*mi + c, k0);
#pragma unroll
        for (int ni = 0; ni < 4; ++ni)
          acc[mi][ni] = __builtin_amdgcn_mfma_f32_16x16x32_bf16(af, xf[ni], acc[mi][ni], 0, 0, 0);
      }
    }
    // D: col=token 16ni+c, rows d_local=16mi+4g+r -> scratch [token][36] quad writes
#pragma unroll
    for (int mi = 0; mi < 2; ++mi) {
      float bq[4];
#pragma unroll
      for (int r = 0; r < 4; ++r) bq[r] = bias[hd0 + 16*mi + 4*g + r];
#pragma unroll
      for (int ni = 0; ni < 4; ++ni) {
        s16x4 pk;
#pragma unroll
        for (int r = 0; r < 4; ++r) pk[r] = f2bf(acc[mi][ni][r] + bq[r]);
        *(s16x4*)(SC + (16*ni + c) * 36 + 16*mi + 4*g) = pk;
      }
    }
    // read back: lane c = token 16ni+c, 8 consecutive d at 8g (2 x b64, conflict-free)
#pragma unroll
    for (int ni = 0; ni < 4; ++ni) {
      const short* p = SC + (16*ni + c) * 36 + 8*g;
      U8 u;
      u.h[0] = *(const s16x4*)p;
      u.h[1] = *(const s16x4*)(p + 4);
      F[ni] = u.v;
    }
  };
  projQK(wq_bf, qw, qb, QB);
  projQK(wk_bf, kw, kb, KA);

  // ---- V projection -> bounce [d_local][token] -> A-frags (lane=d, 8 consec tokens) ----
  {
    f32x4 acc[4][2] = {};   // [token tile][d tile]
#pragma unroll
    for (int kk = 0; kk < 8; ++kk) {
      const int k0 = kk * 32 + 8 * g;
      s16x8 xf[4];
#pragma unroll
      for (int mi = 0; mi < 4; ++mi) xf[mi] = *(const s16x8*)(XN + (16*mi + c) * 264 + k0);
#pragma unroll
      for (int ni = 0; ni < 2; ++ni) {
        s16x8 bf = wfragG(wv_bf, vw, hd0 + 16*ni + c, k0);
#pragma unroll
        for (int mi = 0; mi < 4; ++mi)
          acc[mi][ni] = __builtin_amdgcn_mfma_f32_16x16x32_bf16(xf[mi], bf, acc[mi][ni], 0, 0, 0);
      }
    }
    float bvv[2];
#pragma unroll
    for (int ni = 0; ni < 2; ++ni) bvv[ni] = vb[hd0 + 16*ni + c];
    // D: col=d_local 16ni+c, rows token 16mi+4g+r; un-normalize by SN[token]
#pragma unroll
    for (int mi = 0; mi < 4; ++mi) {
      f32x4 sn4 = *(const f32x4*)(SN + 16*mi + 4*g);
#pragma unroll
      for (int ni = 0; ni < 2; ++ni) {
        s16x4 pk;
#pragma unroll
        for (int r = 0; r < 4; ++r) pk[r] = f2bf(acc[mi][ni][r] * sn4[r] + bvv[ni]);
        *(s16x4*)(SC + (16*ni + c) * 76 + 16*mi + 4*g) = pk;
      }
    }
#pragma unroll
    for (int vd = 0; vd < 2; ++vd)
#pragma unroll
      for (int k2 = 0; k2 < 2; ++k2) {
        const short* p = SC + (16*vd + c) * 76 + 32*k2 + 8*g;
        U8 u;
        u.h[0] = *(const s16x4*)p;
        u.h[1] = *(const s16x4*)(p + 4);
        VA[vd][k2] = u.v;
      }
  }
  __syncthreads();   // all XN reads done -> AN (aliasing XN) may be written

  // ---- attention per q-half: S^T (16 q at a time) -> softmax -> P bounce -> PV -> AN ----
  const f32x4 zf = {0.f, 0.f, 0.f, 0.f};
#pragma unroll
  for (int hi = 0; hi < 2; ++hi) {
#pragma unroll
    for (int n2 = 0; n2 < 2; ++n2) {
      const int qi = 2*hi + n2;
      f32x4 sacc[4];
#pragma unroll
      for (int kt = 0; kt < 4; ++kt)
        sacc[kt] = __builtin_amdgcn_mfma_f32_16x16x32_bf16(KA[kt], QB[qi], zf, 0, 0, 0);
      // lane (c,g): q = 16qi+c, keys 16kt+4g+r
      const int qrow = 16*qi + c;
      float sm = 0.f;
#pragma unroll
      for (int kt = 0; kt < 4; ++kt) {
        h16x4 mlv = *(const h16x4*)(MH + qrow * 68 + 16*kt + 4*g);
#pragma unroll
        for (int r = 0; r < 4; ++r) {
          float e = exp2f(sacc[kt][r] * C1 + (float)mlv[r]);
          sacc[kt][r] = e;
          sm += e;
        }
      }
      sm += __shfl_xor(sm, 16, 64);
      sm += __shfl_xor(sm, 32, 64);
      const float rs = 1.0f / sm;
      // P bounce: [q_local 16n2+c][key 16kt+4g] quads
#pragma unroll
      for (int kt = 0; kt < 4; ++kt) {
        s16x4 pk;
#pragma unroll
        for (int r = 0; r < 4; ++r) pk[r] = f2bf(sacc[kt][r] * rs);
        *(s16x4*)(SC + (16*n2 + c) * 76 + 16*kt + 4*g) = pk;
      }
    }
    // PV: A=V (lane=d, 8 consec keys), B=P (lane=q, 8 consec keys) -> D col=q, row=d
    f32x4 pacc[2][2] = {};   // [vd][qt]
#pragma unroll
    for (int qt = 0; qt < 2; ++qt)
#pragma unroll
      for (int k2 = 0; k2 < 2; ++k2) {
        const short* p = SC + (16*qt + c) * 76 + 32*k2 + 8*g;
        U8 u;
        u.h[0] = *(const s16x4*)p;
        u.h[1] = *(const s16x4*)(p + 4);
        s16x8 PBf = u.v;
#pragma unroll
        for (int vd = 0; vd < 2; ++vd)
          pacc[vd][qt] = __builtin_amdgcn_mfma_f32_16x16x32_bf16(VA[vd][k2], PBf, pacc[vd][qt], 0, 0, 0);
      }
    // AN write: row q = 32hi+16qt+c, cols d = hd0+16vd+4g..+3 (b64)
#pragma unroll
    for (int vd = 0; vd < 2; ++vd)
#pragma unroll
      for (int qt = 0; qt < 2; ++qt)
        *(s16x4*)(AN + (32*hi + 16*qt + c) * 264 + hd0 + 16*vd + 4*g) = pks4(pacc[vd][qt]);
  }
  __syncthreads();

  // ---- P4: final projection, wave w -> out cols 32w..32w+31 ----
  {
    f32x4 facc[4][2] = {};
#pragma unroll
    for (int kk = 0; kk < 8; ++kk) {
      const int k0 = kk * 32 + 8 * g;
      s16x8 afr[4];
#pragma unroll
      for (int mi = 0; mi < 4; ++mi) afr[mi] = *(const s16x8*)(AN + (16*mi + c) * 264 + k0);
#pragma unroll
      for (int ni = 0; ni < 2; ++ni) {
        s16x8 bfr = wfragG(wp_bf, pw, 32*w + 16*ni + c, k0);
#pragma unroll
        for (int mi = 0; mi < 4; ++mi)
          facc[mi][ni] = __builtin_amdgcn_mfma_f32_16x16x32_bf16(afr[mi], bfr, facc[mi][ni], 0, 0, 0);
      }
    }
    float bpv[2];
#pragma unroll
    for (int ni = 0; ni < 2; ++ni) bpv[ni] = pb[32*w + 16*ni + c];
    float* og = out + (size_t)b * 16384;
#pragma unroll
    for (int mi = 0; mi < 4; ++mi)
#pragma unroll
      for (int ni = 0; ni < 2; ++ni)
#pragma unroll
        for (int r = 0; r < 4; ++r)
          og[(16*mi + 4*g + r) * 256 + 32*w + 16*ni + c] = facc[mi][ni][r] + bpv[ni];
  }
}

extern "C" void kernel_launch(void* const* d_in, const int* in_sizes, int n_in,
                              void* d_out, int out_size, void* d_ws, size_t ws_size,
                              hipStream_t stream) {
  const float* x    = (const float*)d_in[0];
  const float* mask = (const float*)d_in[1];
  const float* qw   = (const float*)d_in[2];
  const float* qb   = (const float*)d_in[3];
  const float* kw   = (const float*)d_in[4];
  const float* kb   = (const float*)d_in[5];
  const float* vw   = (const float*)d_in[6];
  const float* vb   = (const float*)d_in[7];
  const float* pw   = (const float*)d_in[8];
  const float* pb   = (const float*)d_in[9];
  float* out = (float*)d_out;

  if (ws_size >= 4u * 65536u * sizeof(short)) {
    short* wsb = (short*)d_ws;
    prep_weights<<<256, 256, 0, stream>>>(qw, kw, vw, pw, wsb);
    wattn<true><<<4096, 512, 0, stream>>>(x, mask, qw, qb, kw, kb, vw, vb, pw, pb, wsb, out);
  } else {
    wattn<false><<<4096, 512, 0, stream>>>(x, mask, qw, qb, kw, kb, vw, vb, pw, pb, nullptr, out);
  }
}

// Round 12
// 338.557 us; speedup vs baseline: 2.0476x; 1.0116x over previous
//
#include <hip/hip_runtime.h>

#define GAIN  0.0625f                // 1/sqrt(256)
#define LOG2E 1.4426950408889634f
#define C1    (0.17677669529663687f * 1.4426950408889634f)   // (1/sqrt(32))*log2e

typedef float f32x4 __attribute__((ext_vector_type(4)));
typedef short s16x8 __attribute__((ext_vector_type(8)));
typedef short s16x4 __attribute__((ext_vector_type(4)));
typedef _Float16 h16x4 __attribute__((ext_vector_type(4)));

union U8 { s16x4 h[2]; s16x8 v; };

static __device__ __forceinline__ short f2bf(float f) {
  union { float f; unsigned u; } v; v.f = f;
  unsigned u = v.u;
  u += 0x7fffu + ((u >> 16) & 1u);   // RNE
  return (short)(u >> 16);
}
static __device__ __forceinline__ s16x4 pks4(const f32x4& v) {
  s16x4 p;
#pragma unroll
  for (int r = 0; r < 4; ++r) p[r] = f2bf(v[r]);
  return p;
}

__global__ void prep_weights(const float* __restrict__ qw, const float* __restrict__ kw,
                             const float* __restrict__ vw, const float* __restrict__ pw,
                             short* __restrict__ wsb) {
  int i = blockIdx.x * 256 + threadIdx.x;   // 0..65535
  wsb[i]          = f2bf(qw[i] * GAIN);
  wsb[i + 65536]  = f2bf(kw[i] * GAIN);
  wsb[i + 131072] = f2bf(vw[i] * GAIN);
  wsb[i + 196608] = f2bf(pw[i] * GAIN);
}

// ---- LDS layout (bytes) ----
// XN: bf16 [64 tok][256] = 32768, XOR-swizzled: storage_col = logical_col ^ ((row&7)<<3)
//     (shorts; kills the 8-way bank conflict of stride-256 b128 row reads).
//     AN aliases it after projections, same swizzle invariant.
// MH: f16 [64][68] = 8704 (mask * log2e)
// SC: per-wave scratch 4864 B x 8 waves = 38912
//     (Q/K bounce [64][36] stride 72B; V/P bounce [32][76] stride 152B)
// SN: f32 [64] = 256
// total 80640 -> 2 blocks/CU
#define OFF_XN 0
#define OFF_MH 32768
#define OFF_SC 41472
#define OFF_SN 80384
#define LDS_TOTAL 80640

template<bool BF16W>
__global__ __launch_bounds__(512, 4)
void wattn(const float* __restrict__ x, const float* __restrict__ mask,
           const float* __restrict__ qw, const float* __restrict__ qb,
           const float* __restrict__ kw, const float* __restrict__ kb,
           const float* __restrict__ vw, const float* __restrict__ vb,
           const float* __restrict__ pw, const float* __restrict__ pb,
           const short* __restrict__ wsb, float* __restrict__ out)
{
  __shared__ __align__(16) char smem[LDS_TOTAL];
  const int tid  = threadIdx.x;
  const int lane = tid & 63;
  const int w    = tid >> 6;     // wave 0..7 = head
  const int c    = lane & 15;
  const int g    = lane >> 4;    // 0..3
  const int b    = blockIdx.x;
  const int sw   = (c & 7) << 3; // read/write swizzle for rows of the form 16*k + c

  const float* xg = x + (size_t)b * 16384;

  short*     XN = (short*)(smem + OFF_XN);
  _Float16*  MH = (_Float16*)(smem + OFF_MH);
  float*     SN = (float*)(smem + OFF_SN);
  short*     SC = (short*)(smem + OFF_SC) + w * 2432;   // 4864 B per wave
  short*     AN = XN;                                   // alias after projections

  const short* wq_bf = wsb;
  const short* wk_bf = wsb + 65536;
  const short* wv_bf = wsb + 131072;
  const short* wp_bf = wsb + 196608;

  auto wfragG = [&](const short* wb, const float* wf, int row, int k0) -> s16x8 {
    s16x8 r;
    if constexpr (BF16W) {
      r = *(const s16x8*)(wb + row * 256 + k0);
    } else {
      const f32x4* p = (const f32x4*)(wf + row * 256 + k0);
      f32x4 a = p[0], b2 = p[1];
#pragma unroll
      for (int j = 0; j < 4; ++j) { r[j] = f2bf(a[j] * GAIN); r[j+4] = f2bf(b2[j] * GAIN); }
    }
    return r;
  };

  // ---- P0: coalesced x load, row norms via wave reduce, swizzled XN write; mask -> f16 ----
  {
    f32x4 xv[8];
    float ssu[8];
#pragma unroll
    for (int u = 0; u < 8; ++u) {
      xv[u] = *(const f32x4*)(xg + (u * 512 + tid) * 4);
      ssu[u] = xv[u][0]*xv[u][0] + xv[u][1]*xv[u][1] + xv[u][2]*xv[u][2] + xv[u][3]*xv[u][3];
    }
#pragma unroll
    for (int u = 0; u < 8; ++u)
#pragma unroll
      for (int d = 1; d < 64; d <<= 1) ssu[u] += __shfl_xor(ssu[u], d, 64);
    const int wsw = w << 3;   // rows written are 8u+w -> row&7 == w
#pragma unroll
    for (int u = 0; u < 8; ++u) {
      const int row = 8 * u + w;
      float s = fmaxf(sqrtf(ssu[u]), 1e-12f);
      float inv = 1.0f / s;
      if (lane == 0) SN[row] = s;
      s16x4 pk;
#pragma unroll
      for (int e = 0; e < 4; ++e) pk[e] = f2bf(xv[u][e] * inv);
      *(s16x4*)(XN + row * 256 + ((lane * 4) ^ wsw)) = pk;
    }
    // mask: thread t -> 8 consecutive floats (coalesced), scale by log2e, store f16
    const f32x4* msrc = (const f32x4*)(mask + (size_t)b * 4096 + tid * 8);
    const int mrow = tid >> 3, mcol = (tid & 7) * 8;
    f32x4 m0 = msrc[0], m1 = msrc[1];
    h16x4 h0, h1;
#pragma unroll
    for (int e = 0; e < 4; ++e) { h0[e] = (_Float16)(m0[e] * LOG2E); h1[e] = (_Float16)(m1[e] * LOG2E); }
    *(h16x4*)(MH + mrow * 68 + mcol)     = h0;
    *(h16x4*)(MH + mrow * 68 + mcol + 4) = h1;
  }
  __syncthreads();

  const int hd0 = 32 * w;   // this wave's head channel base
  s16x8 QB[4], KA[4], VA[2][2];

  // ---- Q/K projection + wave-local LDS bounce -> operand-layout frags ----
  auto projQK = [&](const short* wb, const float* wf, const float* bias, s16x8* F) {
    f32x4 acc[2][4] = {};
#pragma unroll
    for (int kk = 0; kk < 8; ++kk) {
      const int k0 = kk * 32 + 8 * g;
      s16x8 xf[4];
#pragma unroll
      for (int ni = 0; ni < 4; ++ni)
        xf[ni] = *(const s16x8*)(XN + (16*ni + c) * 256 + (k0 ^ sw));
#pragma unroll
      for (int mi = 0; mi < 2; ++mi) {
        s16x8 af = wfragG(wb, wf, hd0 + 16*mi + c, k0);
#pragma unroll
        for (int ni = 0; ni < 4; ++ni)
          acc[mi][ni] = __builtin_amdgcn_mfma_f32_16x16x32_bf16(af, xf[ni], acc[mi][ni], 0, 0, 0);
      }
    }
    // D: col=token 16ni+c, rows d_local=16mi+4g+r -> scratch [token][36] quad writes
#pragma unroll
    for (int mi = 0; mi < 2; ++mi) {
      float bq[4];
#pragma unroll
      for (int r = 0; r < 4; ++r) bq[r] = bias[hd0 + 16*mi + 4*g + r];
#pragma unroll
      for (int ni = 0; ni < 4; ++ni) {
        s16x4 pk;
#pragma unroll
        for (int r = 0; r < 4; ++r) pk[r] = f2bf(acc[mi][ni][r] + bq[r]);
        *(s16x4*)(SC + (16*ni + c) * 36 + 16*mi + 4*g) = pk;
      }
    }
    // read back: lane c = token 16ni+c, 8 consecutive d at 8g (2 x b64)
#pragma unroll
    for (int ni = 0; ni < 4; ++ni) {
      const short* p = SC + (16*ni + c) * 36 + 8*g;
      U8 u;
      u.h[0] = *(const s16x4*)p;
      u.h[1] = *(const s16x4*)(p + 4);
      F[ni] = u.v;
    }
  };
  projQK(wq_bf, qw, qb, QB);
  projQK(wk_bf, kw, kb, KA);

  // ---- V projection -> bounce [d_local][token] -> A-frags (lane=d, 8 consec tokens) ----
  {
    f32x4 acc[4][2] = {};   // [token tile][d tile]
#pragma unroll
    for (int kk = 0; kk < 8; ++kk) {
      const int k0 = kk * 32 + 8 * g;
      s16x8 xf[4];
#pragma unroll
      for (int mi = 0; mi < 4; ++mi)
        xf[mi] = *(const s16x8*)(XN + (16*mi + c) * 256 + (k0 ^ sw));
#pragma unroll
      for (int ni = 0; ni < 2; ++ni) {
        s16x8 bf = wfragG(wv_bf, vw, hd0 + 16*ni + c, k0);
#pragma unroll
        for (int mi = 0; mi < 4; ++mi)
          acc[mi][ni] = __builtin_amdgcn_mfma_f32_16x16x32_bf16(xf[mi], bf, acc[mi][ni], 0, 0, 0);
      }
    }
    float bvv[2];
#pragma unroll
    for (int ni = 0; ni < 2; ++ni) bvv[ni] = vb[hd0 + 16*ni + c];
    // D: col=d_local 16ni+c, rows token 16mi+4g+r; un-normalize by SN[token]
#pragma unroll
    for (int mi = 0; mi < 4; ++mi) {
      f32x4 sn4 = *(const f32x4*)(SN + 16*mi + 4*g);
#pragma unroll
      for (int ni = 0; ni < 2; ++ni) {
        s16x4 pk;
#pragma unroll
        for (int r = 0; r < 4; ++r) pk[r] = f2bf(acc[mi][ni][r] * sn4[r] + bvv[ni]);
        *(s16x4*)(SC + (16*ni + c) * 76 + 16*mi + 4*g) = pk;
      }
    }
#pragma unroll
    for (int vd = 0; vd < 2; ++vd)
#pragma unroll
      for (int k2 = 0; k2 < 2; ++k2) {
        const short* p = SC + (16*vd + c) * 76 + 32*k2 + 8*g;
        U8 u;
        u.h[0] = *(const s16x4*)p;
        u.h[1] = *(const s16x4*)(p + 4);
        VA[vd][k2] = u.v;
      }
  }
  __syncthreads();   // all XN reads done -> AN (aliasing XN) may be written

  // ---- attention per q-half: S^T (16 q at a time) -> softmax -> P bounce -> PV -> AN ----
  const f32x4 zf = {0.f, 0.f, 0.f, 0.f};
#pragma unroll
  for (int hi = 0; hi < 2; ++hi) {
#pragma unroll
    for (int n2 = 0; n2 < 2; ++n2) {
      const int qi = 2*hi + n2;
      f32x4 sacc[4];
#pragma unroll
      for (int kt = 0; kt < 4; ++kt)
        sacc[kt] = __builtin_amdgcn_mfma_f32_16x16x32_bf16(KA[kt], QB[qi], zf, 0, 0, 0);
      // lane (c,g): q = 16qi+c, keys 16kt+4g+r
      const int qrow = 16*qi + c;
      float sm = 0.f;
#pragma unroll
      for (int kt = 0; kt < 4; ++kt) {
        h16x4 mlv = *(const h16x4*)(MH + qrow * 68 + 16*kt + 4*g);
#pragma unroll
        for (int r = 0; r < 4; ++r) {
          float e = exp2f(sacc[kt][r] * C1 + (float)mlv[r]);
          sacc[kt][r] = e;
          sm += e;
        }
      }
      sm += __shfl_xor(sm, 16, 64);
      sm += __shfl_xor(sm, 32, 64);
      const float rs = 1.0f / sm;
      // P bounce: [q_local 16n2+c][key 16kt+4g] quads
#pragma unroll
      for (int kt = 0; kt < 4; ++kt) {
        s16x4 pk;
#pragma unroll
        for (int r = 0; r < 4; ++r) pk[r] = f2bf(sacc[kt][r] * rs);
        *(s16x4*)(SC + (16*n2 + c) * 76 + 16*kt + 4*g) = pk;
      }
    }
    // PV: A=V (lane=d, 8 consec keys), B=P (lane=q, 8 consec keys) -> D col=q, row=d
    f32x4 pacc[2][2] = {};   // [vd][qt]
#pragma unroll
    for (int qt = 0; qt < 2; ++qt)
#pragma unroll
      for (int k2 = 0; k2 < 2; ++k2) {
        const short* p = SC + (16*qt + c) * 76 + 32*k2 + 8*g;
        U8 u;
        u.h[0] = *(const s16x4*)p;
        u.h[1] = *(const s16x4*)(p + 4);
        s16x8 PBf = u.v;
#pragma unroll
        for (int vd = 0; vd < 2; ++vd)
          pacc[vd][qt] = __builtin_amdgcn_mfma_f32_16x16x32_bf16(VA[vd][k2], PBf, pacc[vd][qt], 0, 0, 0);
      }
    // AN write: row q = 32hi+16qt+c, cols d = hd0+16vd+4g (swizzled b64 quads)
#pragma unroll
    for (int vd = 0; vd < 2; ++vd)
#pragma unroll
      for (int qt = 0; qt < 2; ++qt)
        *(s16x4*)(AN + (32*hi + 16*qt + c) * 256 + ((hd0 + 16*vd + 4*g) ^ sw)) = pks4(pacc[vd][qt]);
  }
  __syncthreads();

  // ---- P4: final projection, wave w -> out cols 32w..32w+31 ----
  {
    f32x4 facc[4][2] = {};
#pragma unroll
    for (int kk = 0; kk < 8; ++kk) {
      const int k0 = kk * 32 + 8 * g;
      s16x8 afr[4];
#pragma unroll
      for (int mi = 0; mi < 4; ++mi)
        afr[mi] = *(const s16x8*)(AN + (16*mi + c) * 256 + (k0 ^ sw));
#pragma unroll
      for (int ni = 0; ni < 2; ++ni) {
        s16x8 bfr = wfragG(wp_bf, pw, 32*w + 16*ni + c, k0);
#pragma unroll
        for (int mi = 0; mi < 4; ++mi)
          facc[mi][ni] = __builtin_amdgcn_mfma_f32_16x16x32_bf16(afr[mi], bfr, facc[mi][ni], 0, 0, 0);
      }
    }
    float bpv[2];
#pragma unroll
    for (int ni = 0; ni < 2; ++ni) bpv[ni] = pb[32*w + 16*ni + c];
    float* og = out + (size_t)b * 16384;
#pragma unroll
    for (int mi = 0; mi < 4; ++mi)
#pragma unroll
      for (int ni = 0; ni < 2; ++ni)
#pragma unroll
        for (int r = 0; r < 4; ++r)
          og[(16*mi + 4*g + r) * 256 + 32*w + 16*ni + c] = facc[mi][ni][r] + bpv[ni];
  }
}

extern "C" void kernel_launch(void* const* d_in, const int* in_sizes, int n_in,
                              void* d_out, int out_size, void* d_ws, size_t ws_size,
                              hipStream_t stream) {
  const float* x    = (const float*)d_in[0];
  const float* mask = (const float*)d_in[1];
  const float* qw   = (const float*)d_in[2];
  const float* qb   = (const float*)d_in[3];
  const float* kw   = (const float*)d_in[4];
  const float* kb   = (const float*)d_in[5];
  const float* vw   = (const float*)d_in[6];
  const float* vb   = (const float*)d_in[7];
  const float* pw   = (const float*)d_in[8];
  const float* pb   = (const float*)d_in[9];
  float* out = (float*)d_out;

  if (ws_size >= 4u * 65536u * sizeof(short)) {
    short* wsb = (short*)d_ws;
    prep_weights<<<256, 256, 0, stream>>>(qw, kw, vw, pw, wsb);
    wattn<true><<<4096, 512, 0, stream>>>(x, mask, qw, qb, kw, kb, vw, vb, pw, pb, wsb, out);
  } else {
    wattn<false><<<4096, 512, 0, stream>>>(x, mask, qw, qb, kw, kb, vw, vb, pw, pb, nullptr, out);
  }
}